// Round 4
// baseline (73.142 us; speedup 1.0000x reference)
//
#include <hip/hip_runtime.h>

#define PAD 10
#define CS 128
#define CSP 148           // CS + 2*PAD
#define AH 4000
#define AW 4000
#define RPT 4             // output rows per thread

__global__ __launch_bounds__(256) void shift_bicubic_kernel(
    const float* __restrict__ matrix,
    const float* __restrict__ theta,
    float* __restrict__ out)
{
    const int n   = blockIdx.x;          // tile index 0..1023
    const int i0  = n >> 5;              // tile row
    const int i1  = n & 31;              // tile col
    const int c   = threadIdx.x & 127;   // column within tile
    const int sub = threadIdx.x >> 7;    // 0..1
    const int r0  = blockIdx.y * (2*RPT) + sub*RPT;  // first of RPT rows
    const int w   = i1 * CS + c;
    const int h0  = i0 * CS + r0;
    if (w >= AW || h0 >= AH) return;

    const float t00 = theta[n*6+0], t01 = theta[n*6+1], t02 = theta[n*6+2];
    const float t10 = theta[n*6+3], t11 = theta[n*6+4], t12 = theta[n*6+5];

    const float xs  = (2.0f*(float)(c + PAD) + 1.0f) * (1.0f/148.0f) - 1.0f;
    const float ys0 = (2.0f*(float)(r0 + PAD) + 1.0f) * (1.0f/148.0f) - 1.0f;
    const float bx  = fmaf(t00, xs, t02);
    const float by  = fmaf(t10, xs, t12);

    // tile (0,0) in matrix coords
    const int gr0 = i0*CS - 2*PAD;
    const int gc0 = i1*CS - 2*PAD;

    // block-uniform merged limits (inside tile window AND inside matrix)
    const int lo_c = (gc0 < 0) ? -gc0 : 0;
    const int hi_c = (gc0 + CSP - 1 > AW - 1) ? (AW - 1 - gc0) : (CSP - 1);
    const int lo_r = (gr0 < 0) ? -gr0 : 0;
    const int hi_r = (gr0 + CSP - 1 > AH - 1) ? (AH - 1 - gr0) : (CSP - 1);

    // ---------------- phase 1: coords, weights, branchless prefetch ----------
    float wxv[RPT][4], wyv[RPT][4];
    float4 q[RPT][4];
    int   ixia[RPT], iyia[RPT];
    bool  fastk[RPT];

    #pragma unroll
    for (int k = 0; k < RPT; ++k) {
        const float ysk = fmaf((float)k, 2.0f/148.0f, ys0);
        const float gx  = fmaf(t01, ysk, bx);
        const float gy  = fmaf(t11, ysk, by);
        const float ixf = fmaf(gx, 74.0f, 73.5f);   // ((gx+1)*148-1)/2
        const float iyf = fmaf(gy, 74.0f, 73.5f);

        const float fx0 = floorf(ixf);
        const float fy0 = floorf(iyf);
        const float tx  = ixf - fx0;
        const float ty  = iyf - fy0;
        const int  ixi  = (int)fx0;
        const int  iyi  = (int)fy0;
        ixia[k] = ixi; iyia[k] = iyi;

        const float A_ = -0.75f, AP2 = 1.25f, mAP3 = -2.25f;
        const float sx = 1.0f - tx, sy = 1.0f - ty;
        const float tx2 = tx*tx, sx2 = sx*sx;
        const float ty2 = ty*ty, sy2 = sy*sy;
        wxv[k][0] = A_*(tx*sx2);
        wxv[k][3] = A_*(sx*tx2);
        wxv[k][1] = fmaf(tx2, fmaf(AP2, tx, mAP3), 1.0f);
        wxv[k][2] = fmaf(sx2, fmaf(AP2, sx, mAP3), 1.0f);
        wyv[k][0] = A_*(ty*sy2);
        wyv[k][3] = A_*(sy*ty2);
        wyv[k][1] = fmaf(ty2, fmaf(AP2, ty, mAP3), 1.0f);
        wyv[k][2] = fmaf(sy2, fmaf(AP2, sy, mAP3), 1.0f);

        fastk[k] = (ixi - 1 >= lo_c) & (ixi + 2 <= hi_c) &
                   (iyi - 1 >= lo_r) & (iyi + 2 <= hi_r);

        // clamped (always-safe) footprint base in matrix coords
        int mr = gr0 + iyi - 1;  mr = mr < 0 ? 0 : (mr > AH-4 ? AH-4 : mr);
        int mc = gc0 + ixi - 1;  mc = mc < 0 ? 0 : (mc > AW-4 ? AW-4 : mc);
        const float* p = matrix + (size_t)mr * AW + mc;
        __builtin_memcpy(&q[k][0], p,        16);
        __builtin_memcpy(&q[k][1], p + AW,   16);
        __builtin_memcpy(&q[k][2], p + 2*AW, 16);
        __builtin_memcpy(&q[k][3], p + 3*AW, 16);
    }

    // ---------------- phase 2: consume -------------------------------------
    int oidx = h0*AW + w;
    #pragma unroll
    for (int k = 0; k < RPT; ++k) {
        float acc;
        if (fastk[k]) {
            const float4 q0 = q[k][0], q1 = q[k][1], q2 = q[k][2], q3 = q[k][3];
            const float a0 = fmaf(wxv[k][3],q0.w, fmaf(wxv[k][2],q0.z, fmaf(wxv[k][1],q0.y, wxv[k][0]*q0.x)));
            const float a1 = fmaf(wxv[k][3],q1.w, fmaf(wxv[k][2],q1.z, fmaf(wxv[k][1],q1.y, wxv[k][0]*q1.x)));
            const float a2 = fmaf(wxv[k][3],q2.w, fmaf(wxv[k][2],q2.z, fmaf(wxv[k][1],q2.y, wxv[k][0]*q2.x)));
            const float a3 = fmaf(wxv[k][3],q3.w, fmaf(wxv[k][2],q3.z, fmaf(wxv[k][1],q3.y, wxv[k][0]*q3.x)));
            acc = fmaf(wyv[k][3],a3, fmaf(wyv[k][2],a2, fmaf(wyv[k][1],a1, wyv[k][0]*a0)));
        } else {
            acc = 0.0f;
            const int ixi = ixia[k], iyi = iyia[k];
            #pragma unroll
            for (int ky = 0; ky < 4; ++ky) {
                const int row = iyi - 1 + ky;
                const int gr  = gr0 + row;
                const bool rok = (row >= 0) & (row < CSP) & (gr >= 0) & (gr < AH);
                float racc = 0.0f;
                #pragma unroll
                for (int kx = 0; kx < 4; ++kx) {
                    const int col = ixi - 1 + kx;
                    const int gc  = gc0 + col;
                    const bool cok = rok & (col >= 0) & (col < CSP) & (gc >= 0) & (gc < AW);
                    const float v = cok ? matrix[(size_t)gr*AW + gc] : 0.0f;
                    racc = fmaf(wxv[k][kx], v, racc);
                }
                acc = fmaf(wyv[k][ky], racc, acc);
            }
        }
        if (h0 + k < AH) __builtin_nontemporal_store(acc, &out[oidx]);
        oidx += AW;
    }
}

extern "C" void kernel_launch(void* const* d_in, const int* in_sizes, int n_in,
                              void* d_out, int out_size, void* d_ws, size_t ws_size,
                              hipStream_t stream) {
    const float* matrix = (const float*)d_in[0];
    const float* theta  = (const float*)d_in[1];
    float* out = (float*)d_out;

    dim3 block(256, 1, 1);
    dim3 grid(1024, CS/(2*RPT), 1);   // 1024 tiles x 16 row-groups
    shift_bicubic_kernel<<<grid, block, 0, stream>>>(matrix, theta, out);
}

// Round 5
// 53.699 us; speedup vs baseline: 1.3621x; 1.3621x over previous
//
#include <hip/hip_runtime.h>

#define PAD 10
#define CS 128
#define CSP 148           // CS + 2*PAD
#define AH 4000
#define AW 4000
#define RPT 4             // output rows per thread

// Prepare slot S for pixel with sample coords (IXF, IYF):
// save frac/int coords + fast flag, issue 4 clamped (always-safe) float4 loads.
#define PREP(S, IXF, IYF)                                                     \
    do {                                                                      \
        const float fx0_ = floorf(IXF), fy0_ = floorf(IYF);                   \
        txs[S] = (IXF) - fx0_; tys[S] = (IYF) - fy0_;                         \
        const int ixi_ = (int)fx0_, iyi_ = (int)fy0_;                         \
        ixis[S] = ixi_; iyis[S] = iyi_;                                       \
        fasts[S] = (ixi_ - 1 >= lo_c) & (ixi_ + 2 <= hi_c) &                  \
                   (iyi_ - 1 >= lo_r) & (iyi_ + 2 <= hi_r);                   \
        int mr_ = gr0 + iyi_ - 1; mr_ = mr_ < 0 ? 0 : (mr_ > AH-4 ? AH-4 : mr_); \
        int mc_ = gc0 + ixi_ - 1; mc_ = mc_ < 0 ? 0 : (mc_ > AW-4 ? AW-4 : mc_); \
        const float* p_ = matrix + (size_t)mr_ * AW + mc_;                    \
        __builtin_memcpy(&q[S][0], p_,        16);                            \
        __builtin_memcpy(&q[S][1], p_ + AW,   16);                            \
        __builtin_memcpy(&q[S][2], p_ + 2*AW, 16);                            \
        __builtin_memcpy(&q[S][3], p_ + 3*AW, 16);                            \
    } while (0)

__global__ __launch_bounds__(256) void shift_bicubic_kernel(
    const float* __restrict__ matrix,
    const float* __restrict__ theta,
    float* __restrict__ out)
{
    const int n   = blockIdx.x;          // tile index 0..1023
    const int i0  = n >> 5;
    const int i1  = n & 31;
    const int c   = threadIdx.x & 127;
    const int sub = threadIdx.x >> 7;
    const int r0  = blockIdx.y * (2*RPT) + sub*RPT;
    const int w   = i1 * CS + c;
    const int h0  = i0 * CS + r0;
    if (w >= AW || h0 >= AH) return;

    const float t00 = theta[n*6+0], t01 = theta[n*6+1], t02 = theta[n*6+2];
    const float t10 = theta[n*6+3], t11 = theta[n*6+4], t12 = theta[n*6+5];

    const float xs  = (2.0f*(float)(c + PAD) + 1.0f) * (1.0f/148.0f) - 1.0f;
    const float ys0 = (2.0f*(float)(r0 + PAD) + 1.0f) * (1.0f/148.0f) - 1.0f;
    const float bx  = fmaf(t00, xs, t02);
    const float by  = fmaf(t10, xs, t12);

    // sample coords for row k advance affinely: step is exactly t01 / t11
    const float ixf0 = fmaf(fmaf(t01, ys0, bx), 74.0f, 73.5f);
    const float iyf0 = fmaf(fmaf(t11, ys0, by), 74.0f, 73.5f);

    const int gr0 = i0*CS - 2*PAD;
    const int gc0 = i1*CS - 2*PAD;

    const int lo_c = (gc0 < 0) ? -gc0 : 0;
    const int hi_c = (gc0 + CSP - 1 > AW - 1) ? (AW - 1 - gc0) : (CSP - 1);
    const int lo_r = (gr0 < 0) ? -gr0 : 0;
    const int hi_r = (gr0 + CSP - 1 > AH - 1) ? (AH - 1 - gr0) : (CSP - 1);

    // depth-2 pipeline state
    float  txs[2], tys[2];
    int    ixis[2], iyis[2];
    bool   fasts[2];
    float4 q[2][4];

    PREP(0, ixf0, iyf0);

    int oidx = h0*AW + w;
    #pragma unroll
    for (int k = 0; k < RPT; ++k) {
        // ---- issue next iteration's loads (slot (k+1)&1) ----
        if (k + 1 < RPT) {
            const float ixfn = fmaf((float)(k+1), t01, ixf0);
            const float iyfn = fmaf((float)(k+1), t11, iyf0);
            PREP((k+1)&1, ixfn, iyfn);
        }
        // fence: loads above may not sink below; consume below may not hoist
        __builtin_amdgcn_sched_barrier(0);

        // ---- consume slot k&1 ----
        const int   S  = k & 1;
        const float tx = txs[S], ty = tys[S];
        const float A_ = -0.75f, AP2 = 1.25f, mAP3 = -2.25f;
        const float sx = 1.0f - tx, sy = 1.0f - ty;
        const float tx2 = tx*tx, sx2 = sx*sx;
        const float ty2 = ty*ty, sy2 = sy*sy;
        const float wx0 = A_*(tx*sx2);
        const float wx3 = A_*(sx*tx2);
        const float wx1 = fmaf(tx2, fmaf(AP2, tx, mAP3), 1.0f);
        const float wx2 = fmaf(sx2, fmaf(AP2, sx, mAP3), 1.0f);
        const float wy0 = A_*(ty*sy2);
        const float wy3 = A_*(sy*ty2);
        const float wy1 = fmaf(ty2, fmaf(AP2, ty, mAP3), 1.0f);
        const float wy2 = fmaf(sy2, fmaf(AP2, sy, mAP3), 1.0f);

        float acc;
        if (fasts[S]) {
            const float4 q0 = q[S][0], q1 = q[S][1], q2 = q[S][2], q3 = q[S][3];
            const float a0 = fmaf(wx3,q0.w, fmaf(wx2,q0.z, fmaf(wx1,q0.y, wx0*q0.x)));
            const float a1 = fmaf(wx3,q1.w, fmaf(wx2,q1.z, fmaf(wx1,q1.y, wx0*q1.x)));
            const float a2 = fmaf(wx3,q2.w, fmaf(wx2,q2.z, fmaf(wx1,q2.y, wx0*q2.x)));
            const float a3 = fmaf(wx3,q3.w, fmaf(wx2,q3.z, fmaf(wx1,q3.y, wx0*q3.x)));
            acc = fmaf(wy3,a3, fmaf(wy2,a2, fmaf(wy1,a1, wy0*a0)));
        } else {
            const float wxa[4] = {wx0, wx1, wx2, wx3};
            const float wya[4] = {wy0, wy1, wy2, wy3};
            const int ixi = ixis[S], iyi = iyis[S];
            acc = 0.0f;
            #pragma unroll
            for (int ky = 0; ky < 4; ++ky) {
                const int row = iyi - 1 + ky;
                const int gr  = gr0 + row;
                const bool rok = (row >= 0) & (row < CSP) & (gr >= 0) & (gr < AH);
                float racc = 0.0f;
                #pragma unroll
                for (int kx = 0; kx < 4; ++kx) {
                    const int col = ixi - 1 + kx;
                    const int gc  = gc0 + col;
                    const bool cok = rok & (col >= 0) & (col < CSP) & (gc >= 0) & (gc < AW);
                    const float v = cok ? matrix[(size_t)gr*AW + gc] : 0.0f;
                    racc = fmaf(wxa[kx], v, racc);
                }
                acc = fmaf(wya[ky], racc, acc);
            }
        }
        if (h0 + k < AH) __builtin_nontemporal_store(acc, &out[oidx]);
        oidx += AW;
    }
}

extern "C" void kernel_launch(void* const* d_in, const int* in_sizes, int n_in,
                              void* d_out, int out_size, void* d_ws, size_t ws_size,
                              hipStream_t stream) {
    const float* matrix = (const float*)d_in[0];
    const float* theta  = (const float*)d_in[1];
    float* out = (float*)d_out;

    dim3 block(256, 1, 1);
    dim3 grid(1024, CS/(2*RPT), 1);   // 1024 tiles x 16 row-groups
    shift_bicubic_kernel<<<grid, block, 0, stream>>>(matrix, theta, out);
}